// Round 2
// baseline (979.319 us; speedup 1.0000x reference)
//
#include <hip/hip_runtime.h>

// CompetitiveLayer: fixed-point iterations of
//   BF = BT / (1 + K^T @ AF);  AF = AT / (1 + K @ BF);  K = k*k, BT = bt*bt
// then C = AF[:,None] * K * BF[None,:].  N = 4096.
//
// Persistent kernel, 256 blocks (1/CU forced by ~150 KB LDS), each holds a
// 256x256 bf16 slab of K in LDS.
// R8 (post-mortem of R7: per-iter went 7.5 -> 10 us because waves 1-4 all
// polled = 4x agent-scope load pressure on the flag lines at the MALL,
// repeating R5's coherence-flood mistake in milder form):
//  (1) Single-wave poll restored (R6's 1 wave/block), but keep R7's
//      single-wave writer + wave-local vmcnt(0) drain and the reduced
//      barrier count. Per exchange: B1 -> {wave0: reduce+publish+drain+flag
//      || wave1: poll 16-flag line, gather all 16 slices (64 coalesced
//      loads, 4 cols/lane), compute all 256 BF/AF} -> B2.
//      4 barriers/iter (R6 had 8), 1 polling wave/side (R7 had 4).
//  (2) WAR chain unchanged: writer's slot reuse at it+2 is ordered behind
//      ColFlag/RowFlag >= it+1 from every peer, each of which is behind that
//      peer's B2/B4(it) arrival with its gather loads at it consumed.
//  (3) NITER=20 kept: absmax bit-identical (3.814697e-06 = bf16 floor) at
//      64/48/32/24/20.

#define NSIDE 4096
#define NBLK  256     // 16 x 16 block grid
#define TPB   1024
#define SR    256
#define SC    256
#define NITER 20
#define FANIN 16

typedef float f32x2 __attribute__((ext_vector_type(2)));

__device__ __forceinline__ unsigned short f32_to_bf16(float f) {
  unsigned u = __float_as_uint(f);
  u += 0x7FFFu + ((u >> 16) & 1u);   // round-to-nearest-even
  return (unsigned short)(u >> 16);
}
__device__ __forceinline__ float bfLO(unsigned q) { return __uint_as_float(q << 16); }
__device__ __forceinline__ float bfHI(unsigned q) { return __uint_as_float(q & 0xFFFF0000u); }

__device__ __forceinline__ float ld_agent_f(const float* p) {
  return __hip_atomic_load(p, __ATOMIC_RELAXED, __HIP_MEMORY_SCOPE_AGENT);
}
__device__ __forceinline__ void st_agent_u(unsigned* p, unsigned v) {
  __hip_atomic_store(p, v, __ATOMIC_RELAXED, __HIP_MEMORY_SCOPE_AGENT);
}
__device__ __forceinline__ unsigned ld_agent_u(const unsigned* p) {
  return __hip_atomic_load(p, __ATOMIC_RELAXED, __HIP_MEMORY_SCOPE_AGENT);
}
__device__ __forceinline__ void st_agent_u64(unsigned long long* p, unsigned long long v) {
  __hip_atomic_store(p, v, __ATOMIC_RELAXED, __HIP_MEMORY_SCOPE_AGENT);
}
__device__ __forceinline__ unsigned long long pack2(f32x2 v) {
  union { f32x2 f; unsigned long long u; } cv; cv.f = v; return cv.u;
}
__device__ __forceinline__ void wait_vm0() {
  asm volatile("s_waitcnt vmcnt(0)" ::: "memory");
}

__global__ void ws_init_kernel(unsigned* flags) {
  const int i = threadIdx.x;
  if (i < 2 * FANIN * FANIN) flags[i] = 0u;   // 512 u32: ColFlag + RowFlag
}

__global__ void __launch_bounds__(TPB) competitive_kernel(
    const float* __restrict__ AT, const float* __restrict__ kmat,
    const float* __restrict__ bt, float* __restrict__ C,
    unsigned* __restrict__ ColFlag, unsigned* __restrict__ RowFlag,
    float* __restrict__ ColData, float* __restrict__ RowData) {

  __shared__ unsigned short slab[SR * SC];   // 128 KB bf16(K), row-major
  __shared__ float scratch[16 * SC];         // col-pass wave partials
  __shared__ float rowsum[SR];               // row-pass totals
  __shared__ float AFs[SR];
  __shared__ float BFs[SC];
  __shared__ float ATs[SR];
  __shared__ float BTs[SC];

  const int t   = threadIdx.x;
  const int bid = blockIdx.x;
  const int br  = bid >> 4;
  const int bc  = bid & 15;
  const int R0  = br * SR;
  const int C0  = bc * SC;

  // ---------------- stage slab: K = k*k as bf16 ----------------
  {
    const int c4 = t & 63;
    const int rh = t >> 6;
#pragma unroll
    for (int s = 0; s < 16; ++s) {
      const int r = s * 16 + rh;
      const float4 v = reinterpret_cast<const float4*>(kmat + (size_t)(R0 + r) * NSIDE + C0)[c4];
      ushort4 u;
      u.x = f32_to_bf16(v.x * v.x);
      u.y = f32_to_bf16(v.y * v.y);
      u.z = f32_to_bf16(v.z * v.z);
      u.w = f32_to_bf16(v.w * v.w);
      *reinterpret_cast<ushort4*>(&slab[r * SC + c4 * 4]) = u;
    }
  }
  if (t < SR) { const float a = AT[R0 + t]; ATs[t] = a; AFs[t] = a; }   // AF_0 = AT
  if (t < SC) { const float b = bt[C0 + t]; BTs[t] = b * b; }
  __syncthreads();

  const int c    = t & 31;   // column-group: cols c*8 .. c*8+7
  const int rg   = t >> 5;   // 0..31
  const int w    = t >> 6;   // wave id 0..15
  const int lane = t & 63;

  for (int it = 0; it < NITER; ++it) {
    const unsigned tag = (unsigned)(it + 1);
    float* CD = ColData + (size_t)(it & 1) * FANIN * NSIDE;   // [16][4096] this parity
    float* RD = RowData + (size_t)(it & 1) * FANIN * NSIDE;

    // ============ column pass: partial_j = sum_i K_ij * AF_i ============
    {
      float a0 = 0.f, a1 = 0.f, a2 = 0.f, a3 = 0.f, a4 = 0.f, a5 = 0.f, a6 = 0.f, a7 = 0.f;
#pragma unroll
      for (int s = 0; s < 8; ++s) {
        const int row = rg + s * 32;
        const float af = AFs[row];
        const uint4 q = *reinterpret_cast<const uint4*>(&slab[row * SC + c * 8]);
        a0 += bfLO(q.x) * af;  a1 += bfHI(q.x) * af;
        a2 += bfLO(q.y) * af;  a3 += bfHI(q.y) * af;
        a4 += bfLO(q.z) * af;  a5 += bfHI(q.z) * af;
        a6 += bfLO(q.w) * af;  a7 += bfHI(q.w) * af;
      }
      a0 += __shfl_down(a0, 32); a1 += __shfl_down(a1, 32);
      a2 += __shfl_down(a2, 32); a3 += __shfl_down(a3, 32);
      a4 += __shfl_down(a4, 32); a5 += __shfl_down(a5, 32);
      a6 += __shfl_down(a6, 32); a7 += __shfl_down(a7, 32);
      if ((t & 63) < 32) {
        float4* dst = reinterpret_cast<float4*>(&scratch[w * SC + c * 8]);
        dst[0] = make_float4(a0, a1, a2, a3);
        dst[1] = make_float4(a4, a5, a6, a7);
      }
    }
    __syncthreads();                                          // B1: scratch ready

    if (w == 0) {
      // wave 0: reduce 16 wave-partials, publish slice + flag (wave-local drain)
      f32x2 s0 = {0.f, 0.f}, s1 = {0.f, 0.f};
#pragma unroll
      for (int ww = 0; ww < 16; ++ww) {
        s0 += *reinterpret_cast<const f32x2*>(&scratch[ww * SC + 2 * lane]);
        s1 += *reinterpret_cast<const f32x2*>(&scratch[ww * SC + 128 + 2 * lane]);
      }
      unsigned long long* dst =
          reinterpret_cast<unsigned long long*>(CD + (size_t)br * NSIDE + C0);
      st_agent_u64(&dst[lane], pack2(s0));        // cols 2l, 2l+1   (coalesced)
      st_agent_u64(&dst[lane + 64], pack2(s1));   // cols 128+2l, ..
      wait_vm0();                                  // slice at coherence point
      if (lane == 0) st_agent_u(&ColFlag[bc * FANIN + br], tag);
    } else if (w == 1) {
      // wave 1: sole poller; then gather all 16 slices, compute all 256 BF
      const unsigned* fp = &ColFlag[bc * FANIN + (lane & 15)];
      unsigned fv;
      do { fv = ld_agent_u(fp); } while (!__all((int)(fv >= tag)));
      asm volatile("" ::: "memory");               // loads below can't hoist
      float t0 = 0.f, t1 = 0.f, t2 = 0.f, t3 = 0.f;
#pragma unroll
      for (int ww = 0; ww < 16; ++ww) {
        const float* src = &CD[(size_t)ww * NSIDE + C0];
        t0 += ld_agent_f(&src[lane]);
        t1 += ld_agent_f(&src[lane + 64]);
        t2 += ld_agent_f(&src[lane + 128]);
        t3 += ld_agent_f(&src[lane + 192]);
      }
      BFs[lane]       = BTs[lane]       / (1.0f + t0);
      BFs[lane + 64]  = BTs[lane + 64]  / (1.0f + t1);
      BFs[lane + 128] = BTs[lane + 128] / (1.0f + t2);
      BFs[lane + 192] = BTs[lane + 192] / (1.0f + t3);
    }
    __syncthreads();                                          // B2: BF ready

    // ============ row pass: partial_i = sum_j K_ij * BF_j ============
    {
      const float4 bv0 = *reinterpret_cast<const float4*>(&BFs[c * 8]);
      const float4 bv1 = *reinterpret_cast<const float4*>(&BFs[c * 8 + 4]);
#pragma unroll
      for (int s = 0; s < 8; ++s) {
        const int row = s * 32 + rg;
        const uint4 q = *reinterpret_cast<const uint4*>(&slab[row * SC + c * 8]);
        const float r0 = bfLO(q.x) * bv0.x + bfHI(q.x) * bv0.y;
        const float r1 = bfLO(q.y) * bv0.z + bfHI(q.y) * bv0.w;
        const float r2 = bfLO(q.z) * bv1.x + bfHI(q.z) * bv1.y;
        const float r3 = bfLO(q.w) * bv1.z + bfHI(q.w) * bv1.w;
        float rs = (r0 + r1) + (r2 + r3);
        rs += __shfl_down(rs, 16, 32);
        rs += __shfl_down(rs, 8, 32);
        rs += __shfl_down(rs, 4, 32);
        rs += __shfl_down(rs, 2, 32);
        rs += __shfl_down(rs, 1, 32);
        if (c == 0) rowsum[row] = rs;
      }
    }
    __syncthreads();                                          // B3: rowsum ready

    if (w == 0) {
      f32x2 r0 = *reinterpret_cast<const f32x2*>(&rowsum[2 * lane]);
      f32x2 r1 = *reinterpret_cast<const f32x2*>(&rowsum[128 + 2 * lane]);
      unsigned long long* dst =
          reinterpret_cast<unsigned long long*>(RD + (size_t)bc * NSIDE + R0);
      st_agent_u64(&dst[lane], pack2(r0));
      st_agent_u64(&dst[lane + 64], pack2(r1));
      wait_vm0();
      if (lane == 0) st_agent_u(&RowFlag[br * FANIN + bc], tag);
    } else if (w == 1) {
      const unsigned* fp = &RowFlag[br * FANIN + (lane & 15)];
      unsigned fv;
      do { fv = ld_agent_u(fp); } while (!__all((int)(fv >= tag)));
      asm volatile("" ::: "memory");
      float t0 = 0.f, t1 = 0.f, t2 = 0.f, t3 = 0.f;
#pragma unroll
      for (int ww = 0; ww < 16; ++ww) {
        const float* src = &RD[(size_t)ww * NSIDE + R0];
        t0 += ld_agent_f(&src[lane]);
        t1 += ld_agent_f(&src[lane + 64]);
        t2 += ld_agent_f(&src[lane + 128]);
        t3 += ld_agent_f(&src[lane + 192]);
      }
      AFs[lane]       = ATs[lane]       / (1.0f + t0);
      AFs[lane + 64]  = ATs[lane + 64]  / (1.0f + t1);
      AFs[lane + 128] = ATs[lane + 128] / (1.0f + t2);
      AFs[lane + 192] = ATs[lane + 192] / (1.0f + t3);
    }
    __syncthreads();                                          // B4: AF ready
  }

  // ---------------- tail: C_ij = AF_i * (k_ij^2) * BF_j  (fp32 K) ----------------
  {
    const int c4 = t & 63;
    const int rh = t >> 6;
#pragma unroll
    for (int s = 0; s < 16; ++s) {
      const int r = s * 16 + rh;
      const size_t off = (size_t)(R0 + r) * NSIDE + C0;
      const float4 v = reinterpret_cast<const float4*>(kmat + off)[c4];
      const float4 bf = *reinterpret_cast<const float4*>(&BFs[c4 * 4]);
      const float af = AFs[r];
      float4 o;
      o.x = af * (v.x * v.x) * bf.x;
      o.y = af * (v.y * v.y) * bf.y;
      o.z = af * (v.z * v.z) * bf.z;
      o.w = af * (v.w * v.w) * bf.w;
      reinterpret_cast<float4*>(C + off)[c4] = o;
    }
  }
}

extern "C" void kernel_launch(void* const* d_in, const int* in_sizes, int n_in,
                              void* d_out, int out_size, void* d_ws, size_t ws_size,
                              hipStream_t stream) {
  const float* AT = (const float*)d_in[0];
  const float* k  = (const float*)d_in[1];
  const float* bt = (const float*)d_in[2];
  float* C = (float*)d_out;

  unsigned* ColFlag = (unsigned*)d_ws;                       // 256 u32
  unsigned* RowFlag = ColFlag + FANIN * FANIN;               // 256 u32
  float* ColData = (float*)((char*)d_ws + 4096);             // [2][16][4096] f32 = 512 KB
  float* RowData = ColData + (size_t)2 * FANIN * NSIDE;      // [2][16][4096] f32 = 512 KB

  hipLaunchKernelGGL(ws_init_kernel, dim3(1), dim3(512), 0, stream, ColFlag);
  hipLaunchKernelGGL(competitive_kernel, dim3(NBLK), dim3(TPB), 0, stream,
                     AT, k, bt, C, ColFlag, RowFlag, ColData, RowData);
}

// Round 3
// 470.162 us; speedup vs baseline: 2.0829x; 2.0829x over previous
//
#include <hip/hip_runtime.h>

// CompetitiveLayer: fixed-point iterations of
//   BF = BT / (1 + K^T @ AF);  AF = AT / (1 + K @ BF);  K = k*k, BT = bt*bt
// then C = AF[:,None] * K * BF[None,:].  N = 4096.
//
// Persistent kernel, 256 blocks (1/CU forced by ~150 KB LDS), each holds a
// 256x256 bf16 slab of K in LDS.
// R9 (post-mortem of R8: 42 us/iter. The gather used __hip_atomic_load,
// and LLVM serializes atomic loads: each was a full ~330ns MALL RTT,
// 64 loads on one wave = ~21 us/exchange. R7/R6 fit the same model with 16
// serialized loads):
//  (1) Atomic gather -> acquire-fence + PLAIN float4 loads.
//      After the poll sees all 16 flags, __builtin_amdgcn_fence(ACQUIRE,
//      "agent") emits buffer_inv sc1 (invalidate this XCD's L1/L2), so
//      plain loads read through to the coherent MALL where the writers'
//      agent-scope stores landed. Plain loads are compiler-pipelined:
//      16 coalesced dwordx4 loads ~= 1-2 RTT total instead of 16-64.
//  (2) Gather layout: lane l sums cols 4l..4l+3 across 16 slices
//      (global_load_dwordx4 each), one float4 divide, one LDS float4 store.
//  (3) Writer path, single polling wave, 4 barriers/iter, NITER=20: as R8.
//      WAR chain unchanged (closes via diagonal peer (br,bc):
//      R.reads(it) < R.ColFlag(it+1) < P.B2(it+1) < P.RowFlag(it+1)
//      < W.B4(it+1) < W.stores(it+2)).

#define NSIDE 4096
#define NBLK  256     // 16 x 16 block grid
#define TPB   1024
#define SR    256
#define SC    256
#define NITER 20
#define FANIN 16

typedef float f32x2 __attribute__((ext_vector_type(2)));

__device__ __forceinline__ unsigned short f32_to_bf16(float f) {
  unsigned u = __float_as_uint(f);
  u += 0x7FFFu + ((u >> 16) & 1u);   // round-to-nearest-even
  return (unsigned short)(u >> 16);
}
__device__ __forceinline__ float bfLO(unsigned q) { return __uint_as_float(q << 16); }
__device__ __forceinline__ float bfHI(unsigned q) { return __uint_as_float(q & 0xFFFF0000u); }

__device__ __forceinline__ void st_agent_u(unsigned* p, unsigned v) {
  __hip_atomic_store(p, v, __ATOMIC_RELAXED, __HIP_MEMORY_SCOPE_AGENT);
}
__device__ __forceinline__ unsigned ld_agent_u(const unsigned* p) {
  return __hip_atomic_load(p, __ATOMIC_RELAXED, __HIP_MEMORY_SCOPE_AGENT);
}
__device__ __forceinline__ void st_agent_u64(unsigned long long* p, unsigned long long v) {
  __hip_atomic_store(p, v, __ATOMIC_RELAXED, __HIP_MEMORY_SCOPE_AGENT);
}
__device__ __forceinline__ unsigned long long pack2(f32x2 v) {
  union { f32x2 f; unsigned long long u; } cv; cv.f = v; return cv.u;
}
__device__ __forceinline__ void wait_vm0() {
  asm volatile("s_waitcnt vmcnt(0)" ::: "memory");
}

__global__ void ws_init_kernel(unsigned* flags) {
  const int i = threadIdx.x;
  if (i < 2 * FANIN * FANIN) flags[i] = 0u;   // 512 u32: ColFlag + RowFlag
}

__global__ void __launch_bounds__(TPB) competitive_kernel(
    const float* __restrict__ AT, const float* __restrict__ kmat,
    const float* __restrict__ bt, float* __restrict__ C,
    unsigned* __restrict__ ColFlag, unsigned* __restrict__ RowFlag,
    float* __restrict__ ColData, float* __restrict__ RowData) {

  __shared__ unsigned short slab[SR * SC];   // 128 KB bf16(K), row-major
  __shared__ float scratch[16 * SC];         // col-pass wave partials
  __shared__ float rowsum[SR];               // row-pass totals
  __shared__ float AFs[SR];
  __shared__ float BFs[SC];
  __shared__ float ATs[SR];
  __shared__ float BTs[SC];

  const int t   = threadIdx.x;
  const int bid = blockIdx.x;
  const int br  = bid >> 4;
  const int bc  = bid & 15;
  const int R0  = br * SR;
  const int C0  = bc * SC;

  // ---------------- stage slab: K = k*k as bf16 ----------------
  {
    const int c4 = t & 63;
    const int rh = t >> 6;
#pragma unroll
    for (int s = 0; s < 16; ++s) {
      const int r = s * 16 + rh;
      const float4 v = reinterpret_cast<const float4*>(kmat + (size_t)(R0 + r) * NSIDE + C0)[c4];
      ushort4 u;
      u.x = f32_to_bf16(v.x * v.x);
      u.y = f32_to_bf16(v.y * v.y);
      u.z = f32_to_bf16(v.z * v.z);
      u.w = f32_to_bf16(v.w * v.w);
      *reinterpret_cast<ushort4*>(&slab[r * SC + c4 * 4]) = u;
    }
  }
  if (t < SR) { const float a = AT[R0 + t]; ATs[t] = a; AFs[t] = a; }   // AF_0 = AT
  if (t < SC) { const float b = bt[C0 + t]; BTs[t] = b * b; }
  __syncthreads();

  const int c    = t & 31;   // column-group: cols c*8 .. c*8+7
  const int rg   = t >> 5;   // 0..31
  const int w    = t >> 6;   // wave id 0..15
  const int lane = t & 63;

  for (int it = 0; it < NITER; ++it) {
    const unsigned tag = (unsigned)(it + 1);
    float* CD = ColData + (size_t)(it & 1) * FANIN * NSIDE;   // [16][4096] this parity
    float* RD = RowData + (size_t)(it & 1) * FANIN * NSIDE;

    // ============ column pass: partial_j = sum_i K_ij * AF_i ============
    {
      float a0 = 0.f, a1 = 0.f, a2 = 0.f, a3 = 0.f, a4 = 0.f, a5 = 0.f, a6 = 0.f, a7 = 0.f;
#pragma unroll
      for (int s = 0; s < 8; ++s) {
        const int row = rg + s * 32;
        const float af = AFs[row];
        const uint4 q = *reinterpret_cast<const uint4*>(&slab[row * SC + c * 8]);
        a0 += bfLO(q.x) * af;  a1 += bfHI(q.x) * af;
        a2 += bfLO(q.y) * af;  a3 += bfHI(q.y) * af;
        a4 += bfLO(q.z) * af;  a5 += bfHI(q.z) * af;
        a6 += bfLO(q.w) * af;  a7 += bfHI(q.w) * af;
      }
      a0 += __shfl_down(a0, 32); a1 += __shfl_down(a1, 32);
      a2 += __shfl_down(a2, 32); a3 += __shfl_down(a3, 32);
      a4 += __shfl_down(a4, 32); a5 += __shfl_down(a5, 32);
      a6 += __shfl_down(a6, 32); a7 += __shfl_down(a7, 32);
      if ((t & 63) < 32) {
        float4* dst = reinterpret_cast<float4*>(&scratch[w * SC + c * 8]);
        dst[0] = make_float4(a0, a1, a2, a3);
        dst[1] = make_float4(a4, a5, a6, a7);
      }
    }
    __syncthreads();                                          // B1: scratch ready

    if (w == 0) {
      // wave 0: reduce 16 wave-partials, publish slice + flag (wave-local drain)
      f32x2 s0 = {0.f, 0.f}, s1 = {0.f, 0.f};
#pragma unroll
      for (int ww = 0; ww < 16; ++ww) {
        s0 += *reinterpret_cast<const f32x2*>(&scratch[ww * SC + 2 * lane]);
        s1 += *reinterpret_cast<const f32x2*>(&scratch[ww * SC + 128 + 2 * lane]);
      }
      unsigned long long* dst =
          reinterpret_cast<unsigned long long*>(CD + (size_t)br * NSIDE + C0);
      st_agent_u64(&dst[lane], pack2(s0));        // cols 2l, 2l+1   (coalesced)
      st_agent_u64(&dst[lane + 64], pack2(s1));   // cols 128+2l, ..
      wait_vm0();                                  // slice at coherence point
      if (lane == 0) st_agent_u(&ColFlag[bc * FANIN + br], tag);
    } else if (w == 1) {
      // wave 1: sole poller; acquire-fence; pipelined plain gather; 256 BF
      const unsigned* fp = &ColFlag[bc * FANIN + (lane & 15)];
      unsigned fv;
      do { fv = ld_agent_u(fp); } while (!__all((int)(fv >= tag)));
      __builtin_amdgcn_fence(__ATOMIC_ACQUIRE, "agent");  // inv L1/L2 -> read MALL
      float4 tt = make_float4(0.f, 0.f, 0.f, 0.f);
#pragma unroll
      for (int ww = 0; ww < 16; ++ww) {
        const float4 v =
            *reinterpret_cast<const float4*>(&CD[(size_t)ww * NSIDE + C0 + 4 * lane]);
        tt.x += v.x; tt.y += v.y; tt.z += v.z; tt.w += v.w;
      }
      const float4 bt4 = *reinterpret_cast<const float4*>(&BTs[4 * lane]);
      float4 o;
      o.x = bt4.x / (1.0f + tt.x);
      o.y = bt4.y / (1.0f + tt.y);
      o.z = bt4.z / (1.0f + tt.z);
      o.w = bt4.w / (1.0f + tt.w);
      *reinterpret_cast<float4*>(&BFs[4 * lane]) = o;
    }
    __syncthreads();                                          // B2: BF ready

    // ============ row pass: partial_i = sum_j K_ij * BF_j ============
    {
      const float4 bv0 = *reinterpret_cast<const float4*>(&BFs[c * 8]);
      const float4 bv1 = *reinterpret_cast<const float4*>(&BFs[c * 8 + 4]);
#pragma unroll
      for (int s = 0; s < 8; ++s) {
        const int row = s * 32 + rg;
        const uint4 q = *reinterpret_cast<const uint4*>(&slab[row * SC + c * 8]);
        const float r0 = bfLO(q.x) * bv0.x + bfHI(q.x) * bv0.y;
        const float r1 = bfLO(q.y) * bv0.z + bfHI(q.y) * bv0.w;
        const float r2 = bfLO(q.z) * bv1.x + bfHI(q.z) * bv1.y;
        const float r3 = bfLO(q.w) * bv1.z + bfHI(q.w) * bv1.w;
        float rs = (r0 + r1) + (r2 + r3);
        rs += __shfl_down(rs, 16, 32);
        rs += __shfl_down(rs, 8, 32);
        rs += __shfl_down(rs, 4, 32);
        rs += __shfl_down(rs, 2, 32);
        rs += __shfl_down(rs, 1, 32);
        if (c == 0) rowsum[row] = rs;
      }
    }
    __syncthreads();                                          // B3: rowsum ready

    if (w == 0) {
      f32x2 r0 = *reinterpret_cast<const f32x2*>(&rowsum[2 * lane]);
      f32x2 r1 = *reinterpret_cast<const f32x2*>(&rowsum[128 + 2 * lane]);
      unsigned long long* dst =
          reinterpret_cast<unsigned long long*>(RD + (size_t)bc * NSIDE + R0);
      st_agent_u64(&dst[lane], pack2(r0));
      st_agent_u64(&dst[lane + 64], pack2(r1));
      wait_vm0();
      if (lane == 0) st_agent_u(&RowFlag[br * FANIN + bc], tag);
    } else if (w == 1) {
      const unsigned* fp = &RowFlag[br * FANIN + (lane & 15)];
      unsigned fv;
      do { fv = ld_agent_u(fp); } while (!__all((int)(fv >= tag)));
      __builtin_amdgcn_fence(__ATOMIC_ACQUIRE, "agent");
      float4 tt = make_float4(0.f, 0.f, 0.f, 0.f);
#pragma unroll
      for (int ww = 0; ww < 16; ++ww) {
        const float4 v =
            *reinterpret_cast<const float4*>(&RD[(size_t)ww * NSIDE + R0 + 4 * lane]);
        tt.x += v.x; tt.y += v.y; tt.z += v.z; tt.w += v.w;
      }
      const float4 at4 = *reinterpret_cast<const float4*>(&ATs[4 * lane]);
      float4 o;
      o.x = at4.x / (1.0f + tt.x);
      o.y = at4.y / (1.0f + tt.y);
      o.z = at4.z / (1.0f + tt.z);
      o.w = at4.w / (1.0f + tt.w);
      *reinterpret_cast<float4*>(&AFs[4 * lane]) = o;
    }
    __syncthreads();                                          // B4: AF ready
  }

  // ---------------- tail: C_ij = AF_i * (k_ij^2) * BF_j  (fp32 K) ----------------
  {
    const int c4 = t & 63;
    const int rh = t >> 6;
#pragma unroll
    for (int s = 0; s < 16; ++s) {
      const int r = s * 16 + rh;
      const size_t off = (size_t)(R0 + r) * NSIDE + C0;
      const float4 v = reinterpret_cast<const float4*>(kmat + off)[c4];
      const float4 bf = *reinterpret_cast<const float4*>(&BFs[c4 * 4]);
      const float af = AFs[r];
      float4 o;
      o.x = af * (v.x * v.x) * bf.x;
      o.y = af * (v.y * v.y) * bf.y;
      o.z = af * (v.z * v.z) * bf.z;
      o.w = af * (v.w * v.w) * bf.w;
      reinterpret_cast<float4*>(C + off)[c4] = o;
    }
  }
}

extern "C" void kernel_launch(void* const* d_in, const int* in_sizes, int n_in,
                              void* d_out, int out_size, void* d_ws, size_t ws_size,
                              hipStream_t stream) {
  const float* AT = (const float*)d_in[0];
  const float* k  = (const float*)d_in[1];
  const float* bt = (const float*)d_in[2];
  float* C = (float*)d_out;

  unsigned* ColFlag = (unsigned*)d_ws;                       // 256 u32
  unsigned* RowFlag = ColFlag + FANIN * FANIN;               // 256 u32
  float* ColData = (float*)((char*)d_ws + 4096);             // [2][16][4096] f32 = 512 KB
  float* RowData = ColData + (size_t)2 * FANIN * NSIDE;      // [2][16][4096] f32 = 512 KB

  hipLaunchKernelGGL(ws_init_kernel, dim3(1), dim3(512), 0, stream, ColFlag);
  hipLaunchKernelGGL(competitive_kernel, dim3(NBLK), dim3(TPB), 0, stream,
                     AT, k, bt, C, ColFlag, RowFlag, ColData, RowData);
}

// Round 5
// 341.802 us; speedup vs baseline: 2.8652x; 1.3755x over previous
//
#include <hip/hip_runtime.h>

// CompetitiveLayer: fixed-point iterations of
//   BF = BT / (1 + K^T @ AF);  AF = AT / (1 + K @ BF);  K = k*k, BT = bt*bt
// then C = AF[:,None] * K * BF[None,:].  N = 4096.
//
// Persistent kernel, 256 blocks (1/CU forced by ~150 KB LDS), each holds a
// 256x256 bf16 slab of K in LDS.
// R11 (post-mortem of R10: runtime abort. gather8_sc outputs were "=v" not
// "=&v" -- LLVM may alias an output tuple with a later-read input pointer
// pair; load #1 clobbers a pointer before loads #2..8 read it -> wild
// 64-bit address -> fault. Fix + simplification):
//  (1) gather16_sc: ONE asm block, 16 global_load_dwordx4 sc0 sc1 with
//      EARLY-CLOBBER ("=&v") outputs, one s_waitcnt vmcnt(0) inside the
//      block. 16 slices in ~1 MALL RTT. Consumers are data-dependent on
//      the asm outputs, so nothing can hoist above the internal waitcnt.
//      sc0 sc1 loads read through the (non-coherent) XCD L1/L2 to the MALL,
//      where writers' sc1 stores landed after their wave-local vmcnt(0)
//      drain. No fence (R9's whole-L2 invalidate mistake), no serialized
//      atomic chain (R6/R8's cost).
//  (2) VGPR note: occupancy is LDS-bound at 1 block/CU (152KB LDS), so the
//      ~96 VGPRs live in the asm are free -- no batching needed.
//  (3) Everything else as R9 (passed, absmax 3.814697e-06): single-wave
//      writer (sc1 stores + wave-local vmcnt(0) + flag), single polling
//      wave, 4 barriers/iter, NITER=20. WAR chain via diagonal peer:
//      R.reads(it) < R.ColFlag(it+1) < P.B2(it+1) < P.RowFlag(it+1)
//      < W.B4(it+1) < W.stores(it+2).

#define NSIDE 4096
#define NBLK  256     // 16 x 16 block grid
#define TPB   1024
#define SR    256
#define SC    256
#define NITER 20
#define FANIN 16

typedef float f32x2 __attribute__((ext_vector_type(2)));

__device__ __forceinline__ unsigned short f32_to_bf16(float f) {
  unsigned u = __float_as_uint(f);
  u += 0x7FFFu + ((u >> 16) & 1u);   // round-to-nearest-even
  return (unsigned short)(u >> 16);
}
__device__ __forceinline__ float bfLO(unsigned q) { return __uint_as_float(q << 16); }
__device__ __forceinline__ float bfHI(unsigned q) { return __uint_as_float(q & 0xFFFF0000u); }

__device__ __forceinline__ void st_agent_u(unsigned* p, unsigned v) {
  __hip_atomic_store(p, v, __ATOMIC_RELAXED, __HIP_MEMORY_SCOPE_AGENT);
}
__device__ __forceinline__ unsigned ld_agent_u(const unsigned* p) {
  return __hip_atomic_load(p, __ATOMIC_RELAXED, __HIP_MEMORY_SCOPE_AGENT);
}
__device__ __forceinline__ void st_agent_u64(unsigned long long* p, unsigned long long v) {
  __hip_atomic_store(p, v, __ATOMIC_RELAXED, __HIP_MEMORY_SCOPE_AGENT);
}
__device__ __forceinline__ unsigned long long pack2(f32x2 v) {
  union { f32x2 f; unsigned long long u; } cv; cv.f = v; return cv.u;
}
__device__ __forceinline__ void wait_vm0() {
  asm volatile("s_waitcnt vmcnt(0)" ::: "memory");
}
__device__ __forceinline__ float4 f4add(float4 a, float4 b) {
  return make_float4(a.x + b.x, a.y + b.y, a.z + b.z, a.w + b.w);
}

// 16 pipelined coherent 16B loads (slice stride = NSIDE floats), one waitcnt,
// all inside one asm block. Early-clobber outputs: no output/input aliasing.
__device__ __forceinline__ float4 gather16_sc(const float* base) {
  float4 g0, g1, g2, g3, g4, g5, g6, g7, g8, g9, ga, gb, gc, gd, ge, gf;
  const float* p0 = base;
  const float* p1 = base + (size_t)1 * NSIDE;
  const float* p2 = base + (size_t)2 * NSIDE;
  const float* p3 = base + (size_t)3 * NSIDE;
  const float* p4 = base + (size_t)4 * NSIDE;
  const float* p5 = base + (size_t)5 * NSIDE;
  const float* p6 = base + (size_t)6 * NSIDE;
  const float* p7 = base + (size_t)7 * NSIDE;
  const float* p8 = base + (size_t)8 * NSIDE;
  const float* p9 = base + (size_t)9 * NSIDE;
  const float* pa = base + (size_t)10 * NSIDE;
  const float* pb = base + (size_t)11 * NSIDE;
  const float* pc = base + (size_t)12 * NSIDE;
  const float* pd = base + (size_t)13 * NSIDE;
  const float* pe = base + (size_t)14 * NSIDE;
  const float* pf = base + (size_t)15 * NSIDE;
  asm volatile(
      "global_load_dwordx4 %0, %16, off sc0 sc1\n\t"
      "global_load_dwordx4 %1, %17, off sc0 sc1\n\t"
      "global_load_dwordx4 %2, %18, off sc0 sc1\n\t"
      "global_load_dwordx4 %3, %19, off sc0 sc1\n\t"
      "global_load_dwordx4 %4, %20, off sc0 sc1\n\t"
      "global_load_dwordx4 %5, %21, off sc0 sc1\n\t"
      "global_load_dwordx4 %6, %22, off sc0 sc1\n\t"
      "global_load_dwordx4 %7, %23, off sc0 sc1\n\t"
      "global_load_dwordx4 %8, %24, off sc0 sc1\n\t"
      "global_load_dwordx4 %9, %25, off sc0 sc1\n\t"
      "global_load_dwordx4 %10, %26, off sc0 sc1\n\t"
      "global_load_dwordx4 %11, %27, off sc0 sc1\n\t"
      "global_load_dwordx4 %12, %28, off sc0 sc1\n\t"
      "global_load_dwordx4 %13, %29, off sc0 sc1\n\t"
      "global_load_dwordx4 %14, %30, off sc0 sc1\n\t"
      "global_load_dwordx4 %15, %31, off sc0 sc1\n\t"
      "s_waitcnt vmcnt(0)"
      : "=&v"(g0), "=&v"(g1), "=&v"(g2), "=&v"(g3),
        "=&v"(g4), "=&v"(g5), "=&v"(g6), "=&v"(g7),
        "=&v"(g8), "=&v"(g9), "=&v"(ga), "=&v"(gb),
        "=&v"(gc), "=&v"(gd), "=&v"(ge), "=&v"(gf)
      : "v"(p0), "v"(p1), "v"(p2), "v"(p3),
        "v"(p4), "v"(p5), "v"(p6), "v"(p7),
        "v"(p8), "v"(p9), "v"(pa), "v"(pb),
        "v"(pc), "v"(pd), "v"(pe), "v"(pf)
      : "memory");
  const float4 s01 = f4add(f4add(f4add(g0, g1), f4add(g2, g3)),
                           f4add(f4add(g4, g5), f4add(g6, g7)));
  const float4 s23 = f4add(f4add(f4add(g8, g9), f4add(ga, gb)),
                           f4add(f4add(gc, gd), f4add(ge, gf)));
  return f4add(s01, s23);
}

__global__ void ws_init_kernel(unsigned* flags) {
  const int i = threadIdx.x;
  if (i < 2 * FANIN * FANIN) flags[i] = 0u;   // 512 u32: ColFlag + RowFlag
}

__global__ void __launch_bounds__(TPB) competitive_kernel(
    const float* __restrict__ AT, const float* __restrict__ kmat,
    const float* __restrict__ bt, float* __restrict__ C,
    unsigned* __restrict__ ColFlag, unsigned* __restrict__ RowFlag,
    float* __restrict__ ColData, float* __restrict__ RowData) {

  __shared__ unsigned short slab[SR * SC];   // 128 KB bf16(K), row-major
  __shared__ float scratch[16 * SC];         // col-pass wave partials
  __shared__ float rowsum[SR];               // row-pass totals
  __shared__ float AFs[SR];
  __shared__ float BFs[SC];
  __shared__ float ATs[SR];
  __shared__ float BTs[SC];

  const int t   = threadIdx.x;
  const int bid = blockIdx.x;
  const int br  = bid >> 4;
  const int bc  = bid & 15;
  const int R0  = br * SR;
  const int C0  = bc * SC;

  // ---------------- stage slab: K = k*k as bf16 ----------------
  {
    const int c4 = t & 63;
    const int rh = t >> 6;
#pragma unroll
    for (int s = 0; s < 16; ++s) {
      const int r = s * 16 + rh;
      const float4 v = reinterpret_cast<const float4*>(kmat + (size_t)(R0 + r) * NSIDE + C0)[c4];
      ushort4 u;
      u.x = f32_to_bf16(v.x * v.x);
      u.y = f32_to_bf16(v.y * v.y);
      u.z = f32_to_bf16(v.z * v.z);
      u.w = f32_to_bf16(v.w * v.w);
      *reinterpret_cast<ushort4*>(&slab[r * SC + c4 * 4]) = u;
    }
  }
  if (t < SR) { const float a = AT[R0 + t]; ATs[t] = a; AFs[t] = a; }   // AF_0 = AT
  if (t < SC) { const float b = bt[C0 + t]; BTs[t] = b * b; }
  __syncthreads();

  const int c    = t & 31;   // column-group: cols c*8 .. c*8+7
  const int rg   = t >> 5;   // 0..31
  const int w    = t >> 6;   // wave id 0..15
  const int lane = t & 63;

  for (int it = 0; it < NITER; ++it) {
    const unsigned tag = (unsigned)(it + 1);
    float* CD = ColData + (size_t)(it & 1) * FANIN * NSIDE;   // [16][4096] this parity
    float* RD = RowData + (size_t)(it & 1) * FANIN * NSIDE;

    // ============ column pass: partial_j = sum_i K_ij * AF_i ============
    {
      float a0 = 0.f, a1 = 0.f, a2 = 0.f, a3 = 0.f, a4 = 0.f, a5 = 0.f, a6 = 0.f, a7 = 0.f;
#pragma unroll
      for (int s = 0; s < 8; ++s) {
        const int row = rg + s * 32;
        const float af = AFs[row];
        const uint4 q = *reinterpret_cast<const uint4*>(&slab[row * SC + c * 8]);
        a0 += bfLO(q.x) * af;  a1 += bfHI(q.x) * af;
        a2 += bfLO(q.y) * af;  a3 += bfHI(q.y) * af;
        a4 += bfLO(q.z) * af;  a5 += bfHI(q.z) * af;
        a6 += bfLO(q.w) * af;  a7 += bfHI(q.w) * af;
      }
      a0 += __shfl_down(a0, 32); a1 += __shfl_down(a1, 32);
      a2 += __shfl_down(a2, 32); a3 += __shfl_down(a3, 32);
      a4 += __shfl_down(a4, 32); a5 += __shfl_down(a5, 32);
      a6 += __shfl_down(a6, 32); a7 += __shfl_down(a7, 32);
      if ((t & 63) < 32) {
        float4* dst = reinterpret_cast<float4*>(&scratch[w * SC + c * 8]);
        dst[0] = make_float4(a0, a1, a2, a3);
        dst[1] = make_float4(a4, a5, a6, a7);
      }
    }
    __syncthreads();                                          // B1: scratch ready

    if (w == 0) {
      // wave 0: reduce 16 wave-partials, publish slice + flag (wave-local drain)
      f32x2 s0 = {0.f, 0.f}, s1 = {0.f, 0.f};
#pragma unroll
      for (int ww = 0; ww < 16; ++ww) {
        s0 += *reinterpret_cast<const f32x2*>(&scratch[ww * SC + 2 * lane]);
        s1 += *reinterpret_cast<const f32x2*>(&scratch[ww * SC + 128 + 2 * lane]);
      }
      unsigned long long* dst =
          reinterpret_cast<unsigned long long*>(CD + (size_t)br * NSIDE + C0);
      st_agent_u64(&dst[lane], pack2(s0));        // cols 2l, 2l+1   (coalesced)
      st_agent_u64(&dst[lane + 64], pack2(s1));   // cols 128+2l, ..
      wait_vm0();                                  // slice at coherence point
      if (lane == 0) st_agent_u(&ColFlag[bc * FANIN + br], tag);
    } else if (w == 1) {
      // wave 1: sole poller; 1-RTT pipelined coherent gather; 256 BF
      const unsigned* fp = &ColFlag[bc * FANIN + (lane & 15)];
      unsigned fv;
      do { fv = ld_agent_u(fp); } while (!__all((int)(fv >= tag)));
      const float4 tt = gather16_sc(CD + C0 + 4 * lane);
      const float4 bt4 = *reinterpret_cast<const float4*>(&BTs[4 * lane]);
      float4 o;
      o.x = bt4.x / (1.0f + tt.x);
      o.y = bt4.y / (1.0f + tt.y);
      o.z = bt4.z / (1.0f + tt.z);
      o.w = bt4.w / (1.0f + tt.w);
      *reinterpret_cast<float4*>(&BFs[4 * lane]) = o;
    }
    __syncthreads();                                          // B2: BF ready

    // ============ row pass: partial_i = sum_j K_ij * BF_j ============
    {
      const float4 bv0 = *reinterpret_cast<const float4*>(&BFs[c * 8]);
      const float4 bv1 = *reinterpret_cast<const float4*>(&BFs[c * 8 + 4]);
#pragma unroll
      for (int s = 0; s < 8; ++s) {
        const int row = s * 32 + rg;
        const uint4 q = *reinterpret_cast<const uint4*>(&slab[row * SC + c * 8]);
        const float r0 = bfLO(q.x) * bv0.x + bfHI(q.x) * bv0.y;
        const float r1 = bfLO(q.y) * bv0.z + bfHI(q.y) * bv0.w;
        const float r2 = bfLO(q.z) * bv1.x + bfHI(q.z) * bv1.y;
        const float r3 = bfLO(q.w) * bv1.z + bfHI(q.w) * bv1.w;
        float rs = (r0 + r1) + (r2 + r3);
        rs += __shfl_down(rs, 16, 32);
        rs += __shfl_down(rs, 8, 32);
        rs += __shfl_down(rs, 4, 32);
        rs += __shfl_down(rs, 2, 32);
        rs += __shfl_down(rs, 1, 32);
        if (c == 0) rowsum[row] = rs;
      }
    }
    __syncthreads();                                          // B3: rowsum ready

    if (w == 0) {
      f32x2 r0 = *reinterpret_cast<const f32x2*>(&rowsum[2 * lane]);
      f32x2 r1 = *reinterpret_cast<const f32x2*>(&rowsum[128 + 2 * lane]);
      unsigned long long* dst =
          reinterpret_cast<unsigned long long*>(RD + (size_t)bc * NSIDE + R0);
      st_agent_u64(&dst[lane], pack2(r0));
      st_agent_u64(&dst[lane + 64], pack2(r1));
      wait_vm0();
      if (lane == 0) st_agent_u(&RowFlag[br * FANIN + bc], tag);
    } else if (w == 1) {
      const unsigned* fp = &RowFlag[br * FANIN + (lane & 15)];
      unsigned fv;
      do { fv = ld_agent_u(fp); } while (!__all((int)(fv >= tag)));
      const float4 tt = gather16_sc(RD + R0 + 4 * lane);
      const float4 at4 = *reinterpret_cast<const float4*>(&ATs[4 * lane]);
      float4 o;
      o.x = at4.x / (1.0f + tt.x);
      o.y = at4.y / (1.0f + tt.y);
      o.z = at4.z / (1.0f + tt.z);
      o.w = at4.w / (1.0f + tt.w);
      *reinterpret_cast<float4*>(&AFs[4 * lane]) = o;
    }
    __syncthreads();                                          // B4: AF ready
  }

  // ---------------- tail: C_ij = AF_i * (k_ij^2) * BF_j  (fp32 K) ----------------
  {
    const int c4 = t & 63;
    const int rh = t >> 6;
#pragma unroll
    for (int s = 0; s < 16; ++s) {
      const int r = s * 16 + rh;
      const size_t off = (size_t)(R0 + r) * NSIDE + C0;
      const float4 v = reinterpret_cast<const float4*>(kmat + off)[c4];
      const float4 bf = *reinterpret_cast<const float4*>(&BFs[c4 * 4]);
      const float af = AFs[r];
      float4 o;
      o.x = af * (v.x * v.x) * bf.x;
      o.y = af * (v.y * v.y) * bf.y;
      o.z = af * (v.z * v.z) * bf.z;
      o.w = af * (v.w * v.w) * bf.w;
      reinterpret_cast<float4*>(C + off)[c4] = o;
    }
  }
}

extern "C" void kernel_launch(void* const* d_in, const int* in_sizes, int n_in,
                              void* d_out, int out_size, void* d_ws, size_t ws_size,
                              hipStream_t stream) {
  const float* AT = (const float*)d_in[0];
  const float* k  = (const float*)d_in[1];
  const float* bt = (const float*)d_in[2];
  float* C = (float*)d_out;

  unsigned* ColFlag = (unsigned*)d_ws;                       // 256 u32
  unsigned* RowFlag = ColFlag + FANIN * FANIN;               // 256 u32
  float* ColData = (float*)((char*)d_ws + 4096);             // [2][16][4096] f32 = 512 KB
  float* RowData = ColData + (size_t)2 * FANIN * NSIDE;      // [2][16][4096] f32 = 512 KB

  hipLaunchKernelGGL(ws_init_kernel, dim3(1), dim3(512), 0, stream, ColFlag);
  hipLaunchKernelGGL(competitive_kernel, dim3(NBLK), dim3(TPB), 0, stream,
                     AT, k, bt, C, ColFlag, RowFlag, ColData, RowData);
}